// Round 1
// baseline (5481.156 us; speedup 1.0000x reference)
//
#include <hip/hip_runtime.h>
#include <math.h>

#define NN 500000

// ---------------- degree count: deg[c] += 1 for every edge target ----------
__global__ void deg_kernel(const int* __restrict__ col, int* __restrict__ deg, int E) {
    int e = (blockIdx.x * blockDim.x + threadIdx.x) * 4;
    if (e + 3 < E) {
        int4 c = *reinterpret_cast<const int4*>(col + e);
        atomicAdd(&deg[c.x], 1);
        atomicAdd(&deg[c.y], 1);
        atomicAdd(&deg[c.z], 1);
        atomicAdd(&deg[c.w], 1);
    } else {
        for (int k = e; k < E; ++k) atomicAdd(&deg[col[k]], 1);
    }
}

// ---------------- per-node: dinv = rsqrt(deg+1); h1 = x @ W1 ---------------
__global__ void prep_kernel(const float* __restrict__ x, const float* __restrict__ W1,
                            int* degp, float* __restrict__ h1, int N) {
    int i = blockIdx.x * blockDim.x + threadIdx.x;
    if (i >= N) return;
    float d = rsqrtf((float)degp[i] + 1.0f);
    float acc0 = 0.f, acc1 = 0.f, acc2 = 0.f, acc3 = 0.f;
#pragma unroll
    for (int k = 0; k < 9; ++k) {
        float xv = x[i * 9 + k];
        acc0 += xv * W1[k * 4 + 0];
        acc1 += xv * W1[k * 4 + 1];
        acc2 += xv * W1[k * 4 + 2];
        acc3 += xv * W1[k * 4 + 3];
    }
    reinterpret_cast<float4*>(h1)[i] = make_float4(acc0, acc1, acc2, acc3);
    reinterpret_cast<float*>(degp)[i] = d;   // overwrite int deg with float dinv
}

// ---------------- edge scatter, layer 1 (4 features) -----------------------
__device__ __forceinline__ void scat1(int r, int c, const float* __restrict__ dinv,
                                      const float4* __restrict__ h1v, float* agg1) {
    float n = dinv[r] * dinv[c];
    float4 h = h1v[r];
    atomicAdd(&agg1[4 * c + 0], h.x * n);
    atomicAdd(&agg1[4 * c + 1], h.y * n);
    atomicAdd(&agg1[4 * c + 2], h.z * n);
    atomicAdd(&agg1[4 * c + 3], h.w * n);
}

__global__ void scatter1_kernel(const int* __restrict__ row, const int* __restrict__ col,
                                const float* __restrict__ dinv, const float* __restrict__ h1,
                                float* agg1, int E) {
    int e = (blockIdx.x * blockDim.x + threadIdx.x) * 4;
    const float4* h1v = reinterpret_cast<const float4*>(h1);
    if (e + 3 < E) {
        int4 r4 = *reinterpret_cast<const int4*>(row + e);
        int4 c4 = *reinterpret_cast<const int4*>(col + e);
        scat1(r4.x, c4.x, dinv, h1v, agg1);
        scat1(r4.y, c4.y, dinv, h1v, agg1);
        scat1(r4.z, c4.z, dinv, h1v, agg1);
        scat1(r4.w, c4.w, dinv, h1v, agg1);
    } else {
        for (int k = e; k < E; ++k) scat1(row[k], col[k], dinv, h1v, agg1);
    }
}

// ---- per-node: out1 = agg1 + dinv^2*h1 + b1; t = tanh(out1); h2 = t @ W2 --
__global__ void mid_kernel(const float* __restrict__ agg1, const float* __restrict__ h1,
                           const float* __restrict__ dinv, const float* __restrict__ b1,
                           const float* __restrict__ W2, float* __restrict__ h2, int N) {
    int i = blockIdx.x * blockDim.x + threadIdx.x;
    if (i >= N) return;
    float d2 = dinv[i] * dinv[i];
    float4 a = reinterpret_cast<const float4*>(agg1)[i];
    float4 h = reinterpret_cast<const float4*>(h1)[i];
    float t0 = tanhf(a.x + d2 * h.x + b1[0]);
    float t1 = tanhf(a.y + d2 * h.y + b1[1]);
    float t2 = tanhf(a.z + d2 * h.z + b1[2]);
    float t3 = tanhf(a.w + d2 * h.w + b1[3]);
    float o0 = t0 * W2[0] + t1 * W2[2] + t2 * W2[4] + t3 * W2[6];
    float o1 = t0 * W2[1] + t1 * W2[3] + t2 * W2[5] + t3 * W2[7];
    reinterpret_cast<float2*>(h2)[i] = make_float2(o0, o1);
}

// ---------------- edge scatter, layer 2 (2 features) -----------------------
__device__ __forceinline__ void scat2(int r, int c, const float* __restrict__ dinv,
                                      const float2* __restrict__ h2v, float* agg2) {
    float n = dinv[r] * dinv[c];
    float2 h = h2v[r];
    atomicAdd(&agg2[2 * c + 0], h.x * n);
    atomicAdd(&agg2[2 * c + 1], h.y * n);
}

__global__ void scatter2_kernel(const int* __restrict__ row, const int* __restrict__ col,
                                const float* __restrict__ dinv, const float* __restrict__ h2,
                                float* agg2, int E) {
    int e = (blockIdx.x * blockDim.x + threadIdx.x) * 4;
    const float2* h2v = reinterpret_cast<const float2*>(h2);
    if (e + 3 < E) {
        int4 r4 = *reinterpret_cast<const int4*>(row + e);
        int4 c4 = *reinterpret_cast<const int4*>(col + e);
        scat2(r4.x, c4.x, dinv, h2v, agg2);
        scat2(r4.y, c4.y, dinv, h2v, agg2);
        scat2(r4.z, c4.z, dinv, h2v, agg2);
        scat2(r4.w, c4.w, dinv, h2v, agg2);
    } else {
        for (int k = e; k < E; ++k) scat2(row[k], col[k], dinv, h2v, agg2);
    }
}

// ---------------- final: out = agg2 + dinv^2*h2 + b2 -----------------------
__global__ void final_kernel(const float* __restrict__ agg2, const float* __restrict__ h2,
                             const float* __restrict__ dinv, const float* __restrict__ b2,
                             float* __restrict__ out, int N) {
    int i = blockIdx.x * blockDim.x + threadIdx.x;
    if (i >= N) return;
    float d2 = dinv[i] * dinv[i];
    float2 a = reinterpret_cast<const float2*>(agg2)[i];
    float2 h = reinterpret_cast<const float2*>(h2)[i];
    reinterpret_cast<float2*>(out)[i] =
        make_float2(a.x + d2 * h.x + b2[0], a.y + d2 * h.y + b2[1]);
}

extern "C" void kernel_launch(void* const* d_in, const int* in_sizes, int n_in,
                              void* d_out, int out_size, void* d_ws, size_t ws_size,
                              hipStream_t stream) {
    const float* x  = (const float*)d_in[0];
    const int*   ei = (const int*)d_in[1];   // [2, E] int32 (JAX x64 disabled)
    const float* W1 = (const float*)d_in[2];
    const float* b1 = (const float*)d_in[3];
    const float* W2 = (const float*)d_in[4];
    const float* b2 = (const float*)d_in[5];
    float* out = (float*)d_out;

    const int N = NN;
    const int E = in_sizes[1] / 2;           // 16,000,000
    const int* row = ei;                     // edge_index[0] = source
    const int* col = ei + E;                 // edge_index[1] = target

    // workspace layout (bytes): [deg/dinv: 4N][agg1: 16N][agg2: 8N][h1: 16N][h2: 8N]
    char* ws = (char*)d_ws;
    int*   deg  = (int*)ws;
    float* dinv = (float*)ws;
    float* agg1 = (float*)(ws + 4ull  * N);
    float* agg2 = (float*)(ws + 20ull * N);
    float* h1   = (float*)(ws + 28ull * N);
    float* h2   = (float*)(ws + 44ull * N);

    // zero deg + agg1 + agg2 (harness poisons ws with 0xAA each launch)
    hipMemsetAsync(d_ws, 0, (size_t)28 * N, stream);

    const int tb = 256;
    const int egrid = (E / 4 + tb - 1) / tb;
    const int ngrid = (N + tb - 1) / tb;

    deg_kernel     <<<egrid, tb, 0, stream>>>(col, deg, E);
    prep_kernel    <<<ngrid, tb, 0, stream>>>(x, W1, deg, h1, N);
    scatter1_kernel<<<egrid, tb, 0, stream>>>(row, col, dinv, h1, agg1, E);
    mid_kernel     <<<ngrid, tb, 0, stream>>>(agg1, h1, dinv, b1, W2, h2, N);
    scatter2_kernel<<<egrid, tb, 0, stream>>>(row, col, dinv, h2, agg2, E);
    final_kernel   <<<ngrid, tb, 0, stream>>>(agg2, h2, dinv, b2, out, N);
}

// Round 2
// 2548.101 us; speedup vs baseline: 2.1511x; 2.1511x over previous
//
#include <hip/hip_runtime.h>
#include <math.h>

#define NN 500000
#define SCAN_BLK 1024                       // elements per scan block
#define NB ((NN + SCAN_BLK - 1) / SCAN_BLK) // 489 scan blocks

// ---------------- degree histogram: deg[c] += 1 ----------------------------
__global__ void deg_kernel(const int* __restrict__ col, int* __restrict__ deg, int E) {
    int e = (blockIdx.x * blockDim.x + threadIdx.x) * 4;
    if (e + 3 < E) {
        int4 c = *reinterpret_cast<const int4*>(col + e);
        atomicAdd(&deg[c.x], 1);
        atomicAdd(&deg[c.y], 1);
        atomicAdd(&deg[c.z], 1);
        atomicAdd(&deg[c.w], 1);
    } else {
        for (int k = e; k < E; ++k) atomicAdd(&deg[col[k]], 1);
    }
}

// ---------------- scan stage 1: per-1024-block exclusive scan --------------
__global__ void scan1_kernel(const int* __restrict__ deg, int* __restrict__ start,
                             int* __restrict__ blockSum, int N) {
    __shared__ int ls[256];
    int t = threadIdx.x, b = blockIdx.x;
    int base = b * SCAN_BLK + t * 4;
    int v0 = 0, v1 = 0, v2 = 0, v3 = 0;
    if (base + 3 < N) {
        int4 d = *reinterpret_cast<const int4*>(deg + base);
        v0 = d.x; v1 = d.y; v2 = d.z; v3 = d.w;
    } else {
        if (base < N)     v0 = deg[base];
        if (base + 1 < N) v1 = deg[base + 1];
        if (base + 2 < N) v2 = deg[base + 2];
        if (base + 3 < N) v3 = deg[base + 3];
    }
    int tsum = v0 + v1 + v2 + v3;
    ls[t] = tsum;
    __syncthreads();
    for (int off = 1; off < 256; off <<= 1) {
        int v = (t >= off) ? ls[t - off] : 0;
        __syncthreads();
        ls[t] += v;
        __syncthreads();
    }
    int incl = ls[t];
    int excl = incl - tsum;
    if (base < N)     start[base]     = excl;
    if (base + 1 < N) start[base + 1] = excl + v0;
    if (base + 2 < N) start[base + 2] = excl + v0 + v1;
    if (base + 3 < N) start[base + 3] = excl + v0 + v1 + v2;
    if (t == 255) blockSum[b] = incl;
}

// ---------------- scan stage 2: scan the 489 block sums (1 block) ----------
__global__ void scan2_kernel(int* __restrict__ blockSum, int nb) {
    __shared__ int ls[512];
    int t = threadIdx.x;
    int v = (t < nb) ? blockSum[t] : 0;
    ls[t] = v;
    __syncthreads();
    for (int off = 1; off < 512; off <<= 1) {
        int u = (t >= off) ? ls[t - off] : 0;
        __syncthreads();
        ls[t] += u;
        __syncthreads();
    }
    if (t < nb) blockSum[t] = ls[t] - v;  // exclusive
}

// --- prep: finalize scan (start += blockOff, cursor=start), dinv, g1=dinv*h1
__global__ void prep_kernel(const float* __restrict__ x, const float* __restrict__ W1,
                            const int* __restrict__ deg, const int* __restrict__ blockOff,
                            int* __restrict__ start, int* __restrict__ cursor,
                            float* __restrict__ dinv, float* __restrict__ g1, int N) {
    int i = blockIdx.x * blockDim.x + threadIdx.x;
    if (i >= N) return;
    int s = start[i] + blockOff[i >> 10];
    start[i] = s;
    cursor[i] = s;
    float d = rsqrtf((float)deg[i] + 1.0f);
    dinv[i] = d;
    float acc0 = 0.f, acc1 = 0.f, acc2 = 0.f, acc3 = 0.f;
#pragma unroll
    for (int k = 0; k < 9; ++k) {
        float xv = x[i * 9 + k];
        acc0 += xv * W1[k * 4 + 0];
        acc1 += xv * W1[k * 4 + 1];
        acc2 += xv * W1[k * 4 + 2];
        acc3 += xv * W1[k * 4 + 3];
    }
    reinterpret_cast<float4*>(g1)[i] = make_float4(d * acc0, d * acc1, d * acc2, d * acc3);
}

// ---------------- CSR fill: rows_sorted[cursor[c]++] = r -------------------
__global__ void fill_kernel(const int* __restrict__ row, const int* __restrict__ col,
                            int* __restrict__ cursor, int* __restrict__ rows_sorted, int E) {
    int e = (blockIdx.x * blockDim.x + threadIdx.x) * 4;
    if (e + 3 < E) {
        int4 r = *reinterpret_cast<const int4*>(row + e);
        int4 c = *reinterpret_cast<const int4*>(col + e);
        int p;
        p = atomicAdd(&cursor[c.x], 1); rows_sorted[p] = r.x;
        p = atomicAdd(&cursor[c.y], 1); rows_sorted[p] = r.y;
        p = atomicAdd(&cursor[c.z], 1); rows_sorted[p] = r.z;
        p = atomicAdd(&cursor[c.w], 1); rows_sorted[p] = r.w;
    } else {
        for (int k = e; k < E; ++k) {
            int p = atomicAdd(&cursor[col[k]], 1);
            rows_sorted[p] = row[k];
        }
    }
}

// --- gather layer 1 fused with mid: g2 = dinv * tanh(dinv*(Σg1+g1_self)+b1) @ W2
__global__ void gather1_kernel(const int* __restrict__ start, const int* __restrict__ deg,
                               const int* __restrict__ rows_sorted,
                               const float* __restrict__ dinv, const float* __restrict__ g1,
                               const float* __restrict__ b1, const float* __restrict__ W2,
                               float* __restrict__ g2, int N) {
    int i = blockIdx.x * blockDim.x + threadIdx.x;
    if (i >= N) return;
    const float4* g1v = reinterpret_cast<const float4*>(g1);
    float4 acc = g1v[i];  // self-loop: dinv^2*h1 = dinv*g1_self, scale applied below
    int s = start[i], d = deg[i];
    for (int j = s; j < s + d; ++j) {
        int r = rows_sorted[j];
        float4 g = g1v[r];
        acc.x += g.x; acc.y += g.y; acc.z += g.z; acc.w += g.w;
    }
    float di = dinv[i];
    float t0 = tanhf(di * acc.x + b1[0]);
    float t1 = tanhf(di * acc.y + b1[1]);
    float t2 = tanhf(di * acc.z + b1[2]);
    float t3 = tanhf(di * acc.w + b1[3]);
    float o0 = t0 * W2[0] + t1 * W2[2] + t2 * W2[4] + t3 * W2[6];
    float o1 = t0 * W2[1] + t1 * W2[3] + t2 * W2[5] + t3 * W2[7];
    reinterpret_cast<float2*>(g2)[i] = make_float2(di * o0, di * o1);
}

// --- gather layer 2 fused with final: out = dinv*(Σg2+g2_self) + b2 --------
__global__ void gather2_kernel(const int* __restrict__ start, const int* __restrict__ deg,
                               const int* __restrict__ rows_sorted,
                               const float* __restrict__ dinv, const float* __restrict__ g2,
                               const float* __restrict__ b2, float* __restrict__ out, int N) {
    int i = blockIdx.x * blockDim.x + threadIdx.x;
    if (i >= N) return;
    const float2* g2v = reinterpret_cast<const float2*>(g2);
    float2 acc = g2v[i];  // self-loop
    int s = start[i], d = deg[i];
    for (int j = s; j < s + d; ++j) {
        int r = rows_sorted[j];
        float2 g = g2v[r];
        acc.x += g.x; acc.y += g.y;
    }
    float di = dinv[i];
    reinterpret_cast<float2*>(out)[i] =
        make_float2(di * acc.x + b2[0], di * acc.y + b2[1]);
}

extern "C" void kernel_launch(void* const* d_in, const int* in_sizes, int n_in,
                              void* d_out, int out_size, void* d_ws, size_t ws_size,
                              hipStream_t stream) {
    const float* x  = (const float*)d_in[0];
    const int*   ei = (const int*)d_in[1];   // [2, E] int32
    const float* W1 = (const float*)d_in[2];
    const float* b1 = (const float*)d_in[3];
    const float* W2 = (const float*)d_in[4];
    const float* b2 = (const float*)d_in[5];
    float* out = (float*)d_out;

    const int N = NN;
    const int E = in_sizes[1] / 2;           // 16,000,000
    const int* row = ei;                     // edge_index[0] = source
    const int* col = ei + E;                 // edge_index[1] = target

    // ws layout (bytes, all 16B-aligned): deg[0,4N) start[4N,8N) cursor[8N,12N)
    // dinv[12N,16N) g1[16N,32N) g2[32N,40N) blockSum[40N,+4KB) rows_sorted[...E*4)
    char* ws = (char*)d_ws;
    int*   deg      = (int*)ws;
    int*   start    = (int*)(ws + 4ull  * N);
    int*   cursor   = (int*)(ws + 8ull  * N);
    float* dinv     = (float*)(ws + 12ull * N);
    float* g1       = (float*)(ws + 16ull * N);
    float* g2       = (float*)(ws + 32ull * N);
    int*   blockSum = (int*)(ws + 40ull * N);
    int*   rowsS    = (int*)(ws + 40ull * N + 4096);

    hipMemsetAsync(deg, 0, 4ull * N, stream);  // only deg needs zeroing

    const int tb = 256;
    const int egrid = (E / 4 + tb - 1) / tb;
    const int ngrid = (N + tb - 1) / tb;

    deg_kernel    <<<egrid, tb, 0, stream>>>(col, deg, E);
    scan1_kernel  <<<NB, 256, 0, stream>>>(deg, start, blockSum, N);
    scan2_kernel  <<<1, 512, 0, stream>>>(blockSum, NB);
    prep_kernel   <<<ngrid, tb, 0, stream>>>(x, W1, deg, blockSum, start, cursor, dinv, g1, N);
    fill_kernel   <<<egrid, tb, 0, stream>>>(row, col, cursor, rowsS, E);
    gather1_kernel<<<ngrid, tb, 0, stream>>>(start, deg, rowsS, dinv, g1, b1, W2, g2, N);
    gather2_kernel<<<ngrid, tb, 0, stream>>>(start, deg, rowsS, dinv, g2, b2, out, N);
}

// Round 3
// 1006.290 us; speedup vs baseline: 5.4469x; 2.5322x over previous
//
#include <hip/hip_runtime.h>
#include <math.h>

#define NN 500000
#define BSZ 512                      // nodes per bucket
#define NBK ((NN + BSZ - 1) / BSZ)   // 977 buckets
#define CHUNK 16384                  // edges per partition/hist block

// ---------- pass 1: bucket histogram (LDS-staged) --------------------------
__global__ void hist_kernel(const int* __restrict__ col, int* __restrict__ bucketCount, int E) {
    __shared__ int cnt[1024];
    int t = threadIdx.x;
    for (int i = t; i < 1024; i += 256) cnt[i] = 0;
    __syncthreads();
    int base = blockIdx.x * CHUNK;
    int end = base + CHUNK; if (end > E) end = E;
    int j = base + t * 4;
    for (; j + 3 < end; j += 1024) {
        int4 c = *reinterpret_cast<const int4*>(col + j);
        atomicAdd(&cnt[c.x >> 9], 1);
        atomicAdd(&cnt[c.y >> 9], 1);
        atomicAdd(&cnt[c.z >> 9], 1);
        atomicAdd(&cnt[c.w >> 9], 1);
    }
    if (j < end) for (int k = j; k < end; ++k) atomicAdd(&cnt[col[k] >> 9], 1);
    __syncthreads();
    for (int b = t; b < 1024; b += 256)
        if (cnt[b]) atomicAdd(&bucketCount[b], cnt[b]);
}

// ---------- pass 2: exclusive scan of 1024 bucket counts (1 block) ---------
__global__ void scan_kernel(const int* __restrict__ bucketCount, int* __restrict__ bucketStart,
                            int* __restrict__ gcursor) {
    __shared__ int ls[1024];
    int t = threadIdx.x;
    int v = bucketCount[t];
    ls[t] = v;
    __syncthreads();
    for (int off = 1; off < 1024; off <<= 1) {
        int u = (t >= off) ? ls[t - off] : 0;
        __syncthreads();
        ls[t] += u;
        __syncthreads();
    }
    int excl = ls[t] - v;
    bucketStart[t] = excl;
    gcursor[t] = excl;
}

// ---------- pass 3: partition edges into buckets (chunk reservation) -------
__global__ void part_kernel(const int* __restrict__ row, const int* __restrict__ col,
                            int* __restrict__ gcursor, int* __restrict__ recs, int E) {
    __shared__ int cnt[1024];
    __shared__ int basex[1024];
    int t = threadIdx.x;
    for (int i = t; i < 1024; i += 256) cnt[i] = 0;
    __syncthreads();
    int base = blockIdx.x * CHUNK;
    int end = base + CHUNK; if (end > E) end = E;
    // phase A: local bucket counts
    int j = base + t * 4;
    for (; j + 3 < end; j += 1024) {
        int4 c = *reinterpret_cast<const int4*>(col + j);
        atomicAdd(&cnt[c.x >> 9], 1);
        atomicAdd(&cnt[c.y >> 9], 1);
        atomicAdd(&cnt[c.z >> 9], 1);
        atomicAdd(&cnt[c.w >> 9], 1);
    }
    if (j < end) for (int k = j; k < end; ++k) atomicAdd(&cnt[col[k] >> 9], 1);
    __syncthreads();
    // phase B: reserve contiguous space per bucket, reset local cursors
    for (int b = t; b < 1024; b += 256) {
        int c = cnt[b];
        basex[b] = c ? atomicAdd(&gcursor[b], c) : 0;
    }
    __syncthreads();
    for (int b = t; b < 1024; b += 256) cnt[b] = 0;
    __syncthreads();
    // phase C: write packed records at reserved ranks
    j = base + t * 4;
    for (; j + 3 < end; j += 1024) {
        int4 r = *reinterpret_cast<const int4*>(row + j);
        int4 c = *reinterpret_cast<const int4*>(col + j);
        int b, rk;
        b = c.x >> 9; rk = atomicAdd(&cnt[b], 1); recs[basex[b] + rk] = (r.x << 9) | (c.x & 511);
        b = c.y >> 9; rk = atomicAdd(&cnt[b], 1); recs[basex[b] + rk] = (r.y << 9) | (c.y & 511);
        b = c.z >> 9; rk = atomicAdd(&cnt[b], 1); recs[basex[b] + rk] = (r.z << 9) | (c.z & 511);
        b = c.w >> 9; rk = atomicAdd(&cnt[b], 1); recs[basex[b] + rk] = (r.w << 9) | (c.w & 511);
    }
    if (j < end) {
        for (int k = j; k < end; ++k) {
            int b = col[k] >> 9;
            int rk = atomicAdd(&cnt[b], 1);
            recs[basex[b] + rk] = (row[k] << 9) | (col[k] & 511);
        }
    }
}

// ---------- pass 4: per-bucket degree count -> dinv (no atomics) -----------
__global__ void deg_kernel(const int* __restrict__ bucketStart, const int* __restrict__ bucketCount,
                           const int* __restrict__ recs, float* __restrict__ dinv, int N) {
    __shared__ int cnt[BSZ];
    int t = threadIdx.x, b = blockIdx.x;
    for (int i = t; i < BSZ; i += 256) cnt[i] = 0;
    __syncthreads();
    int s = bucketStart[b], e = s + bucketCount[b];
    for (int j = s + t; j < e; j += 256) atomicAdd(&cnt[recs[j] & 511], 1);
    __syncthreads();
    int nodeBase = b * BSZ;
    for (int n = t; n < BSZ; n += 256) {
        int i = nodeBase + n;
        if (i < N) dinv[i] = rsqrtf((float)cnt[n] + 1.0f);
    }
}

// ---------- prep: g1 = dinv * (x @ W1) -------------------------------------
__global__ void prep_kernel(const float* __restrict__ x, const float* __restrict__ W1,
                            const float* __restrict__ dinv, float* __restrict__ g1, int N) {
    int i = blockIdx.x * blockDim.x + threadIdx.x;
    if (i >= N) return;
    float d = dinv[i];
    float acc0 = 0.f, acc1 = 0.f, acc2 = 0.f, acc3 = 0.f;
#pragma unroll
    for (int k = 0; k < 9; ++k) {
        float xv = x[i * 9 + k];
        acc0 += xv * W1[k * 4 + 0];
        acc1 += xv * W1[k * 4 + 1];
        acc2 += xv * W1[k * 4 + 2];
        acc3 += xv * W1[k * 4 + 3];
    }
    reinterpret_cast<float4*>(g1)[i] = make_float4(d * acc0, d * acc1, d * acc2, d * acc3);
}

// ---------- agg layer 1 (LDS accumulate) + mid fused -----------------------
__global__ void agg1_kernel(const int* __restrict__ bucketStart, const int* __restrict__ bucketCount,
                            const int* __restrict__ recs, const float* __restrict__ dinv,
                            const float* __restrict__ g1, const float* __restrict__ b1,
                            const float* __restrict__ W2, float* __restrict__ g2, int N) {
    __shared__ float acc[4][BSZ + 8];
    int t = threadIdx.x, b = blockIdx.x;
    for (int i = t; i < BSZ; i += 256) {
        acc[0][i] = 0.f; acc[1][i] = 0.f; acc[2][i] = 0.f; acc[3][i] = 0.f;
    }
    __syncthreads();
    const float4* g1v = reinterpret_cast<const float4*>(g1);
    int s = bucketStart[b], e = s + bucketCount[b];
    for (int j = s + t; j < e; j += 256) {
        unsigned u = (unsigned)recs[j];
        int r = u >> 9, cl = u & 511;
        float4 g = g1v[r];
        atomicAdd(&acc[0][cl], g.x);
        atomicAdd(&acc[1][cl], g.y);
        atomicAdd(&acc[2][cl], g.z);
        atomicAdd(&acc[3][cl], g.w);
    }
    __syncthreads();
    int nodeBase = b * BSZ;
    for (int n = t; n < BSZ; n += 256) {
        int i = nodeBase + n;
        if (i >= N) continue;
        float4 self = g1v[i];
        float di = dinv[i];
        float t0 = tanhf(di * (acc[0][n] + self.x) + b1[0]);
        float t1 = tanhf(di * (acc[1][n] + self.y) + b1[1]);
        float t2 = tanhf(di * (acc[2][n] + self.z) + b1[2]);
        float t3 = tanhf(di * (acc[3][n] + self.w) + b1[3]);
        float o0 = t0 * W2[0] + t1 * W2[2] + t2 * W2[4] + t3 * W2[6];
        float o1 = t0 * W2[1] + t1 * W2[3] + t2 * W2[5] + t3 * W2[7];
        reinterpret_cast<float2*>(g2)[i] = make_float2(di * o0, di * o1);
    }
}

// ---------- agg layer 2 (LDS accumulate) + final fused ---------------------
__global__ void agg2_kernel(const int* __restrict__ bucketStart, const int* __restrict__ bucketCount,
                            const int* __restrict__ recs, const float* __restrict__ dinv,
                            const float* __restrict__ g2, const float* __restrict__ b2,
                            float* __restrict__ out, int N) {
    __shared__ float acc[2][BSZ + 8];
    int t = threadIdx.x, b = blockIdx.x;
    for (int i = t; i < BSZ; i += 256) { acc[0][i] = 0.f; acc[1][i] = 0.f; }
    __syncthreads();
    const float2* g2v = reinterpret_cast<const float2*>(g2);
    int s = bucketStart[b], e = s + bucketCount[b];
    for (int j = s + t; j < e; j += 256) {
        unsigned u = (unsigned)recs[j];
        int r = u >> 9, cl = u & 511;
        float2 g = g2v[r];
        atomicAdd(&acc[0][cl], g.x);
        atomicAdd(&acc[1][cl], g.y);
    }
    __syncthreads();
    int nodeBase = b * BSZ;
    for (int n = t; n < BSZ; n += 256) {
        int i = nodeBase + n;
        if (i >= N) continue;
        float2 self = g2v[i];
        float di = dinv[i];
        reinterpret_cast<float2*>(out)[i] =
            make_float2(di * (acc[0][n] + self.x) + b2[0],
                        di * (acc[1][n] + self.y) + b2[1]);
    }
}

extern "C" void kernel_launch(void* const* d_in, const int* in_sizes, int n_in,
                              void* d_out, int out_size, void* d_ws, size_t ws_size,
                              hipStream_t stream) {
    const float* x  = (const float*)d_in[0];
    const int*   ei = (const int*)d_in[1];   // [2, E] int32
    const float* W1 = (const float*)d_in[2];
    const float* b1 = (const float*)d_in[3];
    const float* W2 = (const float*)d_in[4];
    const float* b2 = (const float*)d_in[5];
    float* out = (float*)d_out;

    const int N = NN;
    const int E = in_sizes[1] / 2;           // 16,000,000
    const int* row = ei;                     // edge_index[0] = source
    const int* col = ei + E;                 // edge_index[1] = target

    // ws layout (16B aligned):
    // bucketCount[1024] @0, bucketStart[1024] @4K, gcursor[1024] @8K,
    // dinv @16K (2MB), g1 @16K+2M (8MB), g2 @16K+10M (4MB), recs @16K+14M (64MB)
    char* ws = (char*)d_ws;
    int*   bucketCount = (int*)ws;
    int*   bucketStart = (int*)(ws + 4096);
    int*   gcursor     = (int*)(ws + 8192);
    float* dinv        = (float*)(ws + 16384);
    float* g1          = (float*)(ws + 16384 + 2000000ull);
    float* g2          = (float*)(ws + 16384 + 10000000ull);
    int*   recs        = (int*)(ws + 16384 + 14000000ull);

    hipMemsetAsync(bucketCount, 0, 4096, stream);

    const int nchunks = (E + CHUNK - 1) / CHUNK;          // 977
    const int ngrid = (N + 255) / 256;                    // 1954

    hist_kernel<<<nchunks, 256, 0, stream>>>(col, bucketCount, E);
    scan_kernel<<<1, 1024, 0, stream>>>(bucketCount, bucketStart, gcursor);
    part_kernel<<<nchunks, 256, 0, stream>>>(row, col, gcursor, recs, E);
    deg_kernel <<<NBK, 256, 0, stream>>>(bucketStart, bucketCount, recs, dinv, N);
    prep_kernel<<<ngrid, 256, 0, stream>>>(x, W1, dinv, g1, N);
    agg1_kernel<<<NBK, 256, 0, stream>>>(bucketStart, bucketCount, recs, dinv, g1, b1, W2, g2, N);
    agg2_kernel<<<NBK, 256, 0, stream>>>(bucketStart, bucketCount, recs, dinv, g2, b2, out, N);
}